// Round 4
// baseline (226.708 us; speedup 1.0000x reference)
//
#include <hip/hip_runtime.h>
#include <hip/hip_bf16.h>

#define B_  4
#define T_  2048
#define C_  1024
#define H_  16
#define D_  64
#define BH_ (B_*H_)

typedef float  f32x4  __attribute__((ext_vector_type(4)));
typedef __bf16 bf16x8 __attribute__((ext_vector_type(8)));
typedef __bf16 bf16x2 __attribute__((ext_vector_type(2)));

static __device__ __forceinline__ ushort f2bf(float f) {
    union { float f; unsigned u; } x; x.f = f;
    unsigned r = ((x.u >> 16) & 1u) + 0x7fffu;
    return (ushort)((x.u + r) >> 16);
}

static __device__ __forceinline__ uint packbf(float a, float b) {
    bf16x2 v = { (__bf16)a, (__bf16)b };   // v_cvt_pk_bf16_f32
    return __builtin_bit_cast(uint, v);
}

static __device__ __forceinline__ void gload_lds16(const void* g, void* l) {
    __builtin_amdgcn_global_load_lds(
        (const __attribute__((address_space(1))) unsigned int*)g,
        (__attribute__((address_space(3))) unsigned int*)l, 16, 0, 0);
}

template<int N> static __device__ __forceinline__ void waitcnt_vm() {
    if constexpr (N == 0) asm volatile("s_waitcnt vmcnt(0)" ::: "memory");
    else if constexpr (N == 3) asm volatile("s_waitcnt vmcnt(3)" ::: "memory");
    else if constexpr (N == 4) asm volatile("s_waitcnt vmcnt(4)" ::: "memory");
    else static_assert(N == 0 || N == 3 || N == 4);
    __builtin_amdgcn_sched_barrier(0);
}
static __device__ __forceinline__ void lgkm0() {
    asm volatile("s_waitcnt lgkmcnt(0)" ::: "memory");
    __builtin_amdgcn_sched_barrier(0);
}

// ---------------- fp32 -> bf16 elementwise (n % 4 == 0) ----------------
__global__ void cvt_kernel(const float* __restrict__ in, ushort* __restrict__ out, int n) {
    int i = (blockIdx.x * blockDim.x + threadIdx.x) * 4;
    if (i < n) {
        float4 v = *(const float4*)(in + i);
        ushort4 o;
        o.x = f2bf(v.x); o.y = f2bf(v.y); o.z = f2bf(v.z); o.w = f2bf(v.w);
        *(ushort4*)(out + i) = o;
    }
}

// ---------------- W (K x N fp32) -> Wt (N x K bf16) ----------------
__global__ void transpose_cvt_kernel(const float* __restrict__ in, ushort* __restrict__ out,
                                     int K, int N) {
    __shared__ float tile[32][33];
    int k0 = blockIdx.y * 32, n0 = blockIdx.x * 32;
    int tx = threadIdx.x & 31, ty = threadIdx.x >> 5;  // 32 x 8
    #pragma unroll
    for (int r = 0; r < 32; r += 8)
        tile[ty + r][tx] = in[(size_t)(k0 + ty + r) * N + n0 + tx];
    __syncthreads();
    #pragma unroll
    for (int r = 0; r < 32; r += 8)
        out[(size_t)(n0 + ty + r) * K + k0 + tx] = f2bf(tile[tx][ty + r]);
}

// ---------------- V (bh, t, d) bf16 -> Vt (bh, d, t) bf16 ----------------
__global__ void transpose_v_kernel(const ushort* __restrict__ v, ushort* __restrict__ vt) {
    __shared__ ushort tile[64][66];
    int bh = blockIdx.x >> 5;
    int t0 = (blockIdx.x & 31) * 64;
    const ushort* src = v  + ((size_t)bh * T_ + t0) * D_;
    ushort*       dst = vt + (size_t)bh * D_ * T_ + t0;
    int tx = threadIdx.x & 63, ty = threadIdx.x >> 6;  // 64 x 4
    #pragma unroll
    for (int r = 0; r < 64; r += 4)
        tile[ty + r][tx] = src[(size_t)(ty + r) * D_ + tx];
    __syncthreads();
    #pragma unroll
    for (int r = 0; r < 64; r += 4)
        dst[(size_t)(ty + r) * T_ + tx] = tile[tx][ty + r];
}

// ---------------- deep-pipelined GEMM: C = A @ Bt^T (+bias) ----------------
// BK=32, 3 LDS buffers, prefetch distance 2 tiles, counted vmcnt at tile
// boundaries only (T3+T4), setprio around MFMA (T5), XOR-swizzled LDS (T2).
// 512 threads = 8 waves (2 M x 4 N). BM = MF*32, BN = 256.
// Invariants (derived, see journal): staging of tile t+2 into slot (t-1)%3
// is issued only after the trailing barrier that follows all waves'
// lgkmcnt(0) of tile t-1's last reads; reads of tile t+1 only after
// vmcnt(P)+barrier where P = staging instrs/tile.
template<int MF, bool QKV>
__global__ __launch_bounds__(512, 2) void gemm8p_kernel(
    const ushort* __restrict__ A,    // M x 1024 bf16
    const ushort* __restrict__ Bt,   // N x 1024 bf16 (N x K)
    const float*  __restrict__ bias,
    void* __restrict__ outp)
{
    constexpr int NT = 32;                 // K=1024 / BK=32
    constexpr int BM = MF * 32;
    constexpr int APASS = BM / 128, BPASS = 2, P = APASS + BPASS;
    constexpr int ASLOT = BM * 32;         // elems per A slot
    constexpr int BSLOT = 256 * 32;
    __shared__ __align__(16) ushort lds[3 * ASLOT + 3 * BSLOT];
    ushort* sB0 = lds + 3 * ASLOT;

    const int m0 = blockIdx.y * BM, n0 = blockIdx.x * 256;
    const int tid = threadIdx.x, lane = tid & 63;
    const int wv = tid >> 6, wm = wv >> 2, wn = wv & 3;
    const int lr = lane & 15, lh = lane >> 4;
    const int cxor = (lr >> 1) & 3;

    // staging: thread -> row p*128 + (tid>>2), 16B chunk (tid&3); source
    // chunk pre-swizzled so linear LDS dest == swizzled layout (rule #21)
    const int srow = tid >> 2;
    const int sc = (tid & 3) ^ ((tid >> 3) & 3);
    const ushort* Asrc = A  + (size_t)m0 * 1024 + sc * 8;
    const ushort* Bsrc = Bt + (size_t)n0 * 1024 + sc * 8;

    f32x4 acc[MF][4] = {};

    auto stageA = [&](int t, int slot) {
        #pragma unroll
        for (int p = 0; p < APASS; ++p)
            gload_lds16(Asrc + (size_t)(p * 128 + srow) * 1024 + t * 32,
                        (char*)lds + slot * (ASLOT * 2) + p * 8192 + tid * 16);
    };
    auto stageB = [&](int t, int slot) {
        #pragma unroll
        for (int p = 0; p < BPASS; ++p)
            gload_lds16(Bsrc + (size_t)(p * 128 + srow) * 1024 + t * 32,
                        (char*)sB0 + slot * (BSLOT * 2) + p * 8192 + tid * 16);
    };
    auto readA = [&](bf16x8 (&af)[MF], int slot) {
        const char* base = (const char*)lds + slot * (ASLOT * 2);
        #pragma unroll
        for (int mi = 0; mi < MF; ++mi) {
            int row = wm * (MF * 16) + mi * 16 + lr;
            af[mi] = *(const bf16x8*)(base + row * 64 + (lh ^ cxor) * 16);
        }
    };
    auto readB2 = [&](bf16x8 (&bf)[2], int slot, int nh) {
        const char* base = (const char*)sB0 + slot * (BSLOT * 2);
        #pragma unroll
        for (int i = 0; i < 2; ++i) {
            int row = wn * 64 + nh * 32 + i * 16 + lr;
            bf[i] = *(const bf16x8*)(base + row * 64 + (lh ^ cxor) * 16);
        }
    };

    // prologue: stage tiles 0,1
    stageA(0, 0); stageB(0, 0);
    stageA(1, 1); stageB(1, 1);
    waitcnt_vm<P>();                // tile 0 landed (tile 1's P may be in flight)
    __builtin_amdgcn_s_barrier();

    int s0 = 0, s1 = 1, s2 = 2;
    for (int t = 0; t < NT; ++t) {
        bf16x8 af[MF], bf0[2], bf1[2];
        // phase 0
        readA(af, s0);
        readB2(bf0, s0, 0);
        if (t + 2 < NT) stageA(t + 2, s2);
        __builtin_amdgcn_s_barrier();
        lgkm0();
        __builtin_amdgcn_s_setprio(1);
        #pragma unroll
        for (int mi = 0; mi < MF; ++mi) {
            acc[mi][0] = __builtin_amdgcn_mfma_f32_16x16x32_bf16(af[mi], bf0[0], acc[mi][0], 0, 0, 0);
            acc[mi][1] = __builtin_amdgcn_mfma_f32_16x16x32_bf16(af[mi], bf0[1], acc[mi][1], 0, 0, 0);
        }
        __builtin_amdgcn_s_setprio(0);
        // phase 1
        readB2(bf1, s0, 1);
        if (t + 2 < NT) stageB(t + 2, s2);
        if (t < NT - 2) waitcnt_vm<P>(); else waitcnt_vm<0>();   // tile t+1 landed
        __builtin_amdgcn_s_barrier();
        lgkm0();
        __builtin_amdgcn_s_setprio(1);
        #pragma unroll
        for (int mi = 0; mi < MF; ++mi) {
            acc[mi][2] = __builtin_amdgcn_mfma_f32_16x16x32_bf16(af[mi], bf1[0], acc[mi][2], 0, 0, 0);
            acc[mi][3] = __builtin_amdgcn_mfma_f32_16x16x32_bf16(af[mi], bf1[1], acc[mi][3], 0, 0, 0);
        }
        __builtin_amdgcn_s_setprio(0);
        __builtin_amdgcn_s_barrier();   // retire slot s0 (all waves' reads done)
        int tmp = s0; s0 = s1; s1 = s2; s2 = tmp;
    }

    #pragma unroll
    for (int mi = 0; mi < MF; ++mi) {
        #pragma unroll
        for (int ni = 0; ni < 4; ++ni) {
            int col = n0 + wn * 64 + ni * 16 + lr;
            float bv = bias[col];
            if constexpr (QKV) {
                ushort* qkv = (ushort*)outp;
                int which = col >> 10;
                int h = (col & 1023) >> 6;
                int d = col & 63;
                #pragma unroll
                for (int r = 0; r < 4; ++r) {
                    int row = m0 + wm * (MF * 16) + mi * 16 + lh * 4 + r;
                    int b = row >> 11, t = row & 2047;
                    float v = acc[mi][ni][r] + bv;
                    if (which == 0) v *= 0.18033688011112042f;  // 1/8 * log2(e)
                    qkv[(size_t)which * (BH_ * T_ * D_) +
                        (((size_t)(b * H_ + h)) * T_ + t) * D_ + d] = f2bf(v);
                }
            } else {
                float* Cout = (float*)outp;
                #pragma unroll
                for (int r = 0; r < 4; ++r) {
                    int row = m0 + wm * (MF * 16) + mi * 16 + lh * 4 + r;
                    Cout[(size_t)row * C_ + col] = acc[mi][ni][r] + bv;
                }
            }
        }
    }
}

// ---------------- flash attention v4: merged paired q-tiles ----------------
// q pre-scaled by log2(e)/8 -> softmax in exp2 space. Block handles q-tiles
// qtA = p and qtB = 31-p (33 tile-units per block, balanced). K/V fragment
// reads from LDS are SHARED between the two q-tiles (halves LDS read traffic
// in the heavy phase).
__global__ __launch_bounds__(256, 3) void flash_kernel(
    const ushort* __restrict__ qb,  // (bh, t, d) bf16
    const ushort* __restrict__ kb,  // (bh, t, d) bf16
    const ushort* __restrict__ vt,  // (bh, d, t) bf16
    ushort* __restrict__ ob)        // (b*t, 1024) bf16
{
    __shared__ __align__(16) ushort sK[2][64 * 64];
    __shared__ __align__(16) ushort sV[2][64 * 64];
    __shared__ __align__(16) ushort sP[8][16 * 64];
    const int bh  = blockIdx.x >> 4;
    const int pr  = blockIdx.x & 15;
    const int qtA = pr, qtB = 31 - pr;
    const int lane = threadIdx.x & 63, wv = threadIdx.x >> 6;
    const int lr = lane & 15, lh = lane >> 4;

    const ushort* qrowA = qb + ((size_t)bh * T_ + qtA * 64 + wv * 16 + lr) * D_;
    const ushort* qrowB = qb + ((size_t)bh * T_ + qtB * 64 + wv * 16 + lr) * D_;
    bf16x8 qfA0 = *(const bf16x8*)(qrowA + lh * 8);
    bf16x8 qfA1 = *(const bf16x8*)(qrowA + 32 + lh * 8);
    bf16x8 qfB0 = *(const bf16x8*)(qrowB + lh * 8);
    bf16x8 qfB1 = *(const bf16x8*)(qrowB + 32 + lh * 8);

    const int srow = lane >> 3;
    const int scol = ((lane & 7) ^ srow) * 8;
    const ushort* kbase = kb + (size_t)bh * T_ * D_;
    const ushort* vbase = vt + (size_t)bh * D_ * T_;

    const int sw   = (lr & 7) << 4;
    const int off0 = (16 * lh) ^ sw;
    const int off1 = (64 + 16 * lh) ^ sw;

    f32x4 oA[4] = {}, oB[4] = {};
    float mA = -1e30f, lA = 0.f, mB = -1e30f, lB = 0.f;

    auto redmax = [&](float x) {
        x = fmaxf(x, __int_as_float(__builtin_amdgcn_ds_swizzle(__float_as_int(x), 0x401F)));
        x = fmaxf(x, __shfl_xor(x, 32, 64));
        return x;
    };
    auto redsum = [&](float x) {
        x += __int_as_float(__builtin_amdgcn_ds_swizzle(__float_as_int(x), 0x401F));
        x += __shfl_xor(x, 32, 64);
        return x;
    };

    // softmax over one q-tile's S^T (lane: q=lr; k = 16nt+4lh+r), write P
    auto softmax = [&](f32x4 (&s)[4], float& mrow, float& lsum, f32x4 (&o)[4], char* P) {
        float pmax = fmaxf(fmaxf(fmaxf(s[0][0], s[0][1]), fmaxf(s[0][2], s[0][3])),
                           fmaxf(fmaxf(s[1][0], s[1][1]), fmaxf(s[1][2], s[1][3])));
        pmax = fmaxf(pmax, fmaxf(fmaxf(fmaxf(s[2][0], s[2][1]), fmaxf(s[2][2], s[2][3])),
                                 fmaxf(fmaxf(s[3][0], s[3][1]), fmaxf(s[3][2], s[3][3]))));
        pmax = redmax(pmax);
        if (__any(pmax > mrow + 8.f)) {     // defer-max (T13, THR=8, exp2 space)
            float mnew = fmaxf(mrow, pmax);
            float al = __builtin_exp2f(mrow - mnew);
            lsum *= al;
            #pragma unroll
            for (int r = 0; r < 4; ++r) {
                float ar = __shfl(al, lh * 20 + r, 64);  // lane with lr == lh*4+r
                o[0][r] *= ar; o[1][r] *= ar; o[2][r] *= ar; o[3][r] *= ar;
            }
            mrow = mnew;
        }
        float rsum = 0.f;
        uint pk[8];
        #pragma unroll
        for (int nt = 0; nt < 4; ++nt) {
            float p0 = __builtin_exp2f(s[nt][0] - mrow);
            float p1 = __builtin_exp2f(s[nt][1] - mrow);
            float p2 = __builtin_exp2f(s[nt][2] - mrow);
            float p3 = __builtin_exp2f(s[nt][3] - mrow);
            rsum += (p0 + p1) + (p2 + p3);
            pk[nt * 2]     = packbf(p0, p1);
            pk[nt * 2 + 1] = packbf(p2, p3);
        }
        lsum += redsum(rsum);
        char* prow = P + lr * 128;
        #pragma unroll
        for (int nt = 0; nt < 4; ++nt) {
            uint2 w; w.x = pk[nt * 2]; w.y = pk[nt * 2 + 1];
            *(uint2*)(prow + ((32 * nt + 8 * lh) ^ sw)) = w;
        }
    };

    // prologue: stage tile 0
    #pragma unroll
    for (int i = 0; i < 2; ++i) {
        int j = i * 4 + wv;
        gload_lds16(kbase + (size_t)(j * 8 + srow) * D_ + scol, &sK[0][j * 512]);
        gload_lds16(vbase + (size_t)(j * 8 + srow) * T_ + scol, &sV[0][j * 512]);
    }
    __syncthreads();

    for (int kt = 0; kt <= qtB; ++kt) {
        const int cur = kt & 1;
        if (kt < qtB) {
            const int nb = cur ^ 1;
            #pragma unroll
            for (int i = 0; i < 2; ++i) {
                int j = i * 4 + wv;
                gload_lds16(kbase + (size_t)((kt + 1) * 64 + j * 8 + srow) * D_ + scol, &sK[nb][j * 512]);
                gload_lds16(vbase + (size_t)(j * 8 + srow) * T_ + (kt + 1) * 64 + scol, &sV[nb][j * 512]);
            }
        }
        const bool doA = kt <= qtA;
        const char* K0 = (const char*)sK[cur];
        const char* V0 = (const char*)sV[cur];

        // --- QK^T swapped, shared K fragments ---
        f32x4 sa[4], sb[4];
        __builtin_amdgcn_s_setprio(1);
        if (doA) {
            #pragma unroll
            for (int nt = 0; nt < 4; ++nt) {
                const char* krow = K0 + (nt * 16 + lr) * 128;
                bf16x8 k0 = *(const bf16x8*)(krow + off0);
                bf16x8 k1 = *(const bf16x8*)(krow + off1);
                f32x4 a = {0.f, 0.f, 0.f, 0.f};
                a = __builtin_amdgcn_mfma_f32_16x16x32_bf16(k0, qfB0, a, 0, 0, 0);
                a = __builtin_amdgcn_mfma_f32_16x16x32_bf16(k1, qfB1, a, 0, 0, 0);
                sb[nt] = a;
                f32x4 c = {0.f, 0.f, 0.f, 0.f};
                c = __builtin_amdgcn_mfma_f32_16x16x32_bf16(k0, qfA0, c, 0, 0, 0);
                c = __builtin_amdgcn_mfma_f32_16x16x32_bf16(k1, qfA1, c, 0, 0, 0);
                sa[nt] = c;
            }
        } else {
            #pragma unroll
            for (int nt = 0; nt < 4; ++nt) {
                const char* krow = K0 + (nt * 16 + lr) * 128;
                bf16x8 k0 = *(const bf16x8*)(krow + off0);
                bf16x8 k1 = *(const bf16x8*)(krow + off1);
                f32x4 a = {0.f, 0.f, 0.f, 0.f};
                a = __builtin_amdgcn_mfma_f32_16x16x32_bf16(k0, qfB0, a, 0, 0, 0);
                a = __builtin_amdgcn_mfma_f32_16x16x32_bf16(k1, qfB1, a, 0, 0, 0);
                sb[nt] = a;
            }
        }
        __builtin_amdgcn_s_setprio(0);

        if (kt == qtB) {   // diagonal mask for B: k_local > q_local
            #pragma unroll
            for (int nt = 0; nt < 4; ++nt)
                #pragma unroll
                for (int r = 0; r < 4; ++r)
                    if (nt * 16 + lh * 4 + r > wv * 16 + lr) sb[nt][r] = -INFINITY;
        }
        if (doA && kt == qtA) {
            #pragma unroll
            for (int nt = 0; nt < 4; ++nt)
                #pragma unroll
                for (int r = 0; r < 4; ++r)
                    if (nt * 16 + lh * 4 + r > wv * 16 + lr) sa[nt][r] = -INFINITY;
        }

        softmax(sb, mB, lB, oB, (char*)sP[wv]);
        if (doA) softmax(sa, mA, lA, oA, (char*)sP[4 + wv]);
        asm volatile("" ::: "memory");

        bf16x8 pfB0 = *(const bf16x8*)((char*)sP[wv] + lr * 128 + off0);
        bf16x8 pfB1 = *(const bf16x8*)((char*)sP[wv] + lr * 128 + off1);

        // --- PV, shared V fragments ---
        __builtin_amdgcn_s_setprio(1);
        if (doA) {
            bf16x8 pfA0 = *(const bf16x8*)((char*)sP[4 + wv] + lr * 128 + off0);
            bf16x8 pfA1 = *(const bf16x8*)((char*)sP[4 + wv] + lr * 128 + off1);
            #pragma unroll
            for (int dt = 0; dt < 4; ++dt) {
                const char* vrow = V0 + (dt * 16 + lr) * 128;
                bf16x8 v0 = *(const bf16x8*)(vrow + off0);
                bf16x8 v1 = *(const bf16x8*)(vrow + off1);
                oB[dt] = __builtin_amdgcn_mfma_f32_16x16x32_bf16(pfB0, v0, oB[dt], 0, 0, 0);
                oB[dt] = __builtin_amdgcn_mfma_f32_16x16x32_bf16(pfB1, v1, oB[dt], 0, 0, 0);
                oA[dt] = __builtin_amdgcn_mfma_f32_16x16x32_bf16(pfA0, v0, oA[dt], 0, 0, 0);
                oA[dt] = __builtin_amdgcn_mfma_f32_16x16x32_bf16(pfA1, v1, oA[dt], 0, 0, 0);
            }
        } else {
            #pragma unroll
            for (int dt = 0; dt < 4; ++dt) {
                const char* vrow = V0 + (dt * 16 + lr) * 128;
                bf16x8 v0 = *(const bf16x8*)(vrow + off0);
                bf16x8 v1 = *(const bf16x8*)(vrow + off1);
                oB[dt] = __builtin_amdgcn_mfma_f32_16x16x32_bf16(pfB0, v0, oB[dt], 0, 0, 0);
                oB[dt] = __builtin_amdgcn_mfma_f32_16x16x32_bf16(pfB1, v1, oB[dt], 0, 0, 0);
            }
        }
        __builtin_amdgcn_s_setprio(0);
        __syncthreads();
    }

    const int b = bh >> 4, h = bh & 15;
    auto writeout = [&](f32x4 (&o)[4], float lsum, int q0) {
        float inv = 1.f / lsum;
        #pragma unroll
        for (int r = 0; r < 4; ++r) {
            float ir = __shfl(inv, lh * 20 + r, 64);
            int q = q0 + lh * 4 + r;
            #pragma unroll
            for (int dt = 0; dt < 4; ++dt)
                ob[((size_t)b * T_ + q) * C_ + h * 64 + dt * 16 + lr] = f2bf(o[dt][r] * ir);
        }
    };
    writeout(oA, lA, qtA * 64 + wv * 16);
    writeout(oB, lB, qtB * 64 + wv * 16);
}

extern "C" void kernel_launch(void* const* d_in, const int* in_sizes, int n_in,
                              void* d_out, int out_size, void* d_ws, size_t ws_size,
                              hipStream_t stream) {
    const float* x     = (const float*)d_in[0];
    const float* w_qkv = (const float*)d_in[1];
    const float* b_qkv = (const float*)d_in[2];
    const float* w_out = (const float*)d_in[3];
    const float* b_out = (const float*)d_in[4];
    float* out = (float*)d_out;

    char* ws = (char*)d_ws;
    ushort* xb     = (ushort*)(ws + 0);           // 16 MB (aliased: attn out reuses after GEMM1)
    ushort* wqkvT  = (ushort*)(ws + 16777216);    // 6 MB
    ushort* woutT  = (ushort*)(ws + 23068672);    // 2 MB
    ushort* qkv    = (ushort*)(ws + 25165824);    // 48 MB
    ushort* vT     = (ushort*)(ws + 75497472);    // 16 MB
    ushort* attn   = xb;
    ushort* qb = qkv;
    ushort* kb = qkv + (size_t)BH_ * T_ * D_;
    ushort* vb = qkv + (size_t)2 * BH_ * T_ * D_;

    const int nx = B_ * T_ * C_;
    cvt_kernel<<<nx / 4 / 256, 256, 0, stream>>>(x, xb, nx);
    transpose_cvt_kernel<<<dim3(3 * C_ / 32, C_ / 32), 256, 0, stream>>>(w_qkv, wqkvT, C_, 3 * C_);
    transpose_cvt_kernel<<<dim3(C_ / 32, C_ / 32), 256, 0, stream>>>(w_out, woutT, C_, C_);
    gemm8p_kernel<8, true><<<dim3(3 * C_ / 256, B_ * T_ / 256), 512, 0, stream>>>(xb, wqkvT, b_qkv, qkv);
    transpose_v_kernel<<<BH_ * (T_ / 64), 256, 0, stream>>>(vb, vT);
    flash_kernel<<<BH_ * 16, 256, 0, stream>>>(qb, kb, vT, attn);
    gemm8p_kernel<4, false><<<dim3(C_ / 256, B_ * T_ / 128), 512, 0, stream>>>(attn, woutT, b_out, out);
}

// Round 5
// 205.230 us; speedup vs baseline: 1.1047x; 1.1047x over previous
//
#include <hip/hip_runtime.h>
#include <hip/hip_bf16.h>

#define B_  4
#define T_  2048
#define C_  1024
#define H_  16
#define D_  64
#define BH_ (B_*H_)

typedef float  f32x4  __attribute__((ext_vector_type(4)));
typedef __bf16 bf16x8 __attribute__((ext_vector_type(8)));
typedef __bf16 bf16x2 __attribute__((ext_vector_type(2)));

static __device__ __forceinline__ ushort f2bf(float f) {
    union { float f; unsigned u; } x; x.f = f;
    unsigned r = ((x.u >> 16) & 1u) + 0x7fffu;
    return (ushort)((x.u + r) >> 16);
}

static __device__ __forceinline__ uint packbf(float a, float b) {
    bf16x2 v = { (__bf16)a, (__bf16)b };   // v_cvt_pk_bf16_f32
    return __builtin_bit_cast(uint, v);
}

static __device__ __forceinline__ void gload_lds16(const void* g, void* l) {
    __builtin_amdgcn_global_load_lds(
        (const __attribute__((address_space(1))) unsigned int*)g,
        (__attribute__((address_space(3))) unsigned int*)l, 16, 0, 0);
}

template<int N> static __device__ __forceinline__ void waitcnt_vm() {
    if constexpr (N == 0) asm volatile("s_waitcnt vmcnt(0)" ::: "memory");
    else if constexpr (N == 3) asm volatile("s_waitcnt vmcnt(3)" ::: "memory");
    else if constexpr (N == 4) asm volatile("s_waitcnt vmcnt(4)" ::: "memory");
    else static_assert(N == 0 || N == 3 || N == 4);
    __builtin_amdgcn_sched_barrier(0);
}
static __device__ __forceinline__ void lgkm0() {
    asm volatile("s_waitcnt lgkmcnt(0)" ::: "memory");
    __builtin_amdgcn_sched_barrier(0);
}

// ---------------- fp32 -> bf16 elementwise (n % 4 == 0) ----------------
__global__ void cvt_kernel(const float* __restrict__ in, ushort* __restrict__ out, int n) {
    int i = (blockIdx.x * blockDim.x + threadIdx.x) * 4;
    if (i < n) {
        float4 v = *(const float4*)(in + i);
        ushort4 o;
        o.x = f2bf(v.x); o.y = f2bf(v.y); o.z = f2bf(v.z); o.w = f2bf(v.w);
        *(ushort4*)(out + i) = o;
    }
}

// ---------------- W (K x N fp32) -> Wt (N x K bf16) ----------------
__global__ void transpose_cvt_kernel(const float* __restrict__ in, ushort* __restrict__ out,
                                     int K, int N) {
    __shared__ float tile[32][33];
    int k0 = blockIdx.y * 32, n0 = blockIdx.x * 32;
    int tx = threadIdx.x & 31, ty = threadIdx.x >> 5;  // 32 x 8
    #pragma unroll
    for (int r = 0; r < 32; r += 8)
        tile[ty + r][tx] = in[(size_t)(k0 + ty + r) * N + n0 + tx];
    __syncthreads();
    #pragma unroll
    for (int r = 0; r < 32; r += 8)
        out[(size_t)(n0 + ty + r) * K + k0 + tx] = f2bf(tile[tx][ty + r]);
}

// ---------------- V (bh, t, d) bf16 -> Vt (bh, d, t) bf16 ----------------
__global__ void transpose_v_kernel(const ushort* __restrict__ v, ushort* __restrict__ vt) {
    __shared__ ushort tile[64][66];
    int bh = blockIdx.x >> 5;
    int t0 = (blockIdx.x & 31) * 64;
    const ushort* src = v  + ((size_t)bh * T_ + t0) * D_;
    ushort*       dst = vt + (size_t)bh * D_ * T_ + t0;
    int tx = threadIdx.x & 63, ty = threadIdx.x >> 6;  // 64 x 4
    #pragma unroll
    for (int r = 0; r < 64; r += 4)
        tile[ty + r][tx] = src[(size_t)(ty + r) * D_ + tx];
    __syncthreads();
    #pragma unroll
    for (int r = 0; r < 64; r += 4)
        dst[(size_t)(ty + r) * T_ + tx] = tile[tx][ty + r];
}

// ---------------- m201-style GEMM: BM=256, BK=64 (2 K-halves), 8 waves ----------------
// 2 LDS buffers (dbuf), counted vmcnt: half-tile granularity (K-split), stage
// issued 2 half-groups ahead of consumption; vmcnt(PK) guarantees the oldest
// in-flight half-group landed before the barrier that precedes its reads.
// NFR = per-wave N fragments: 4 -> BN=256 (4 phases/tile), 2 -> BN=128 (2 phases).
template<int NFR, bool QKV>
__global__ __launch_bounds__(512, 2) void gemm_hk(
    const ushort* __restrict__ A,    // M x 1024 bf16 (row-major)
    const ushort* __restrict__ Bt,   // N x 1024 bf16 (N x K)
    const float*  __restrict__ bias,
    void* __restrict__ outp)
{
    constexpr int NT   = 16;               // K=1024 / BK=64
    constexpr int BN   = NFR * 64;
    constexpr int ABUF = 32768;             // bytes: 256 rows x 64 k x 2B
    constexpr int BBUF = BN * 128;          // bytes: BN rows x 64 k x 2B
    constexpr int LB   = (NFR == 4) ? 2 : 1;   // B gloads/thread per K-half
    constexpr int PK   = 2 + LB;            // loads per K-half group (A+B)
    __shared__ __align__(16) char lds[2 * ABUF + 2 * BBUF];
    char* ldsB = lds + 2 * ABUF;

    const int m0 = blockIdx.y * 256, n0 = blockIdx.x * BN;
    const int tid = threadIdx.x, lane = tid & 63;
    const int wv = tid >> 6, wm = wv >> 2, wn = wv & 3;
    const int lr = lane & 15, lh = lane >> 4;

    // staging: thread -> row tid>>2 (+p*128), 16B chunk; source chunk
    // pre-swizzled (^ row&3) so linear LDS dest == swizzled layout (rule #21)
    const int sc = (tid & 3) ^ ((tid >> 2) & 3);
    const ushort* aA = A  + (size_t)(m0 + (tid >> 2)) * 1024 + sc * 8;
    const ushort* aB = Bt + (size_t)(n0 + (tid >> 2)) * 1024 + sc * 8;

    // read-side swizzle: chunk = lh ^ (row&3), row&3 == lr&3 for all frags
    const int cxor = (lh ^ (lr & 3)) * 16;
    const int arow = (wm * 128 + lr) * 64 + cxor;
    const int brow = (wn * (NFR * 16) + lr) * 64 + cxor;

    f32x4 acc[8][NFR] = {};

    auto stage_a = [&](int buf, int t, int kh) {
        #pragma unroll
        for (int p = 0; p < 2; ++p)
            gload_lds16(aA + (size_t)p * 131072 + t * 64 + kh * 32,
                        lds + buf * ABUF + kh * 16384 + p * 8192 + tid * 16);
    };
    auto stage_b = [&](int buf, int t, int kh) {
        #pragma unroll
        for (int p = 0; p < LB; ++p)
            gload_lds16(aB + (size_t)p * 131072 + t * 64 + kh * 32,
                        ldsB + buf * BBUF + kh * (BBUF / 2) + p * 8192 + tid * 16);
    };
    auto read_a = [&](bf16x8 (&af)[8], int buf, int kh) {
        const char* base = lds + buf * ABUF + kh * 16384 + arow;
        #pragma unroll
        for (int mi = 0; mi < 8; ++mi) af[mi] = *(const bf16x8*)(base + mi * 1024);
    };
    auto read_b = [&](bf16x8& b0, bf16x8& b1, int buf, int kh, int nh) {
        const char* base = ldsB + buf * BBUF + kh * (BBUF / 2) + brow + nh * 2048;
        b0 = *(const bf16x8*)(base);
        b1 = *(const bf16x8*)(base + 1024);
    };

#define MFMA2(NI, BB0, BB1)                                                          \
    do {                                                                             \
        __builtin_amdgcn_s_setprio(1);                                               \
        _Pragma("unroll")                                                            \
        for (int mi = 0; mi < 8; ++mi) {                                             \
            acc[mi][NI]     = __builtin_amdgcn_mfma_f32_16x16x32_bf16(af[mi], BB0,   \
                                                     acc[mi][NI], 0, 0, 0);          \
            acc[mi][NI + 1] = __builtin_amdgcn_mfma_f32_16x16x32_bf16(af[mi], BB1,   \
                                                     acc[mi][NI + 1], 0, 0, 0);      \
        }                                                                            \
        __builtin_amdgcn_s_setprio(0);                                               \
    } while (0)

    // prologue: stage tile 0 (order: Akh0, Bkh0, Akh1, Bkh1)
    stage_a(0, 0, 0); stage_b(0, 0, 0);
    stage_a(0, 0, 1); stage_b(0, 0, 1);
    waitcnt_vm<PK>();                    // kh0(0) landed
    __builtin_amdgcn_s_barrier();

    for (int t = 0; t < NT; ++t) {
        const int cur = t & 1, nxt = cur ^ 1;
        const bool pf = (t + 1 < NT);
        bf16x8 af[8], b0, b1;
        if constexpr (NFR == 4) {
            // ph1: kh0, ni 0-1
            read_a(af, cur, 0); read_b(b0, b1, cur, 0, 0);
            if (pf) stage_a(nxt, t + 1, 0);
            __builtin_amdgcn_s_barrier();
            lgkm0();
            MFMA2(0, b0, b1);
            // ph2: kh0, ni 2-3
            read_b(b0, b1, cur, 0, 1);
            if (pf) stage_b(nxt, t + 1, 0);
            if (t < NT - 1) waitcnt_vm<4>(); else waitcnt_vm<0>();  // kh1(t) landed
            __builtin_amdgcn_s_barrier();
            lgkm0();
            MFMA2(2, b0, b1);
            // ph3: kh1, ni 0-1
            read_a(af, cur, 1); read_b(b0, b1, cur, 1, 0);
            if (pf) stage_a(nxt, t + 1, 1);
            __builtin_amdgcn_s_barrier();
            lgkm0();
            MFMA2(0, b0, b1);
            // ph4: kh1, ni 2-3
            read_b(b0, b1, cur, 1, 1);
            if (pf) stage_b(nxt, t + 1, 1);
            if (t < NT - 1) waitcnt_vm<4>();                        // kh0(t+1) landed
            __builtin_amdgcn_s_barrier();
            lgkm0();
            MFMA2(2, b0, b1);
        } else {
            // ph1: kh0
            read_a(af, cur, 0); read_b(b0, b1, cur, 0, 0);
            if (pf) { stage_a(nxt, t + 1, 0); stage_b(nxt, t + 1, 0); }
            if (t < NT - 1) waitcnt_vm<3>(); else waitcnt_vm<0>();  // kh1(t) landed
            __builtin_amdgcn_s_barrier();
            lgkm0();
            MFMA2(0, b0, b1);
            // ph2: kh1
            read_a(af, cur, 1); read_b(b0, b1, cur, 1, 0);
            if (pf) { stage_a(nxt, t + 1, 1); stage_b(nxt, t + 1, 1); }
            if (t < NT - 1) waitcnt_vm<3>();                        // kh0(t+1) landed
            __builtin_amdgcn_s_barrier();
            lgkm0();
            MFMA2(0, b0, b1);
        }
    }
#undef MFMA2

    #pragma unroll
    for (int mi = 0; mi < 8; ++mi) {
        #pragma unroll
        for (int ni = 0; ni < NFR; ++ni) {
            int col = n0 + wn * (NFR * 16) + ni * 16 + lr;
            float bv = bias[col];
            if constexpr (QKV) {
                ushort* qkv = (ushort*)outp;
                int which = col >> 10;
                int h = (col & 1023) >> 6;
                int d = col & 63;
                #pragma unroll
                for (int r = 0; r < 4; ++r) {
                    int row = m0 + wm * 128 + mi * 16 + lh * 4 + r;
                    int b = row >> 11, tt = row & 2047;
                    float v = acc[mi][ni][r] + bv;
                    if (which == 0) v *= 0.18033688011112042f;  // 1/8 * log2(e)
                    qkv[(size_t)which * (BH_ * T_ * D_) +
                        (((size_t)(b * H_ + h)) * T_ + tt) * D_ + d] = f2bf(v);
                }
            } else {
                float* Cout = (float*)outp;
                #pragma unroll
                for (int r = 0; r < 4; ++r) {
                    int row = m0 + wm * 128 + mi * 16 + lh * 4 + r;
                    Cout[(size_t)row * C_ + col] = acc[mi][ni][r] + bv;
                }
            }
        }
    }
}

// ---------------- flash attention v3 (R3 verbatim): qt-paired blocks ----------------
// q pre-scaled by log2(e)/8 -> softmax in exp2 space. Block handles q-tiles
// qtA = p and qtB = 31-p: 33 tile-units per block for every p -> balanced grid.
__global__ __launch_bounds__(256, 4) void flash_kernel(
    const ushort* __restrict__ qb,  // (bh, t, d) bf16
    const ushort* __restrict__ kb,  // (bh, t, d) bf16
    const ushort* __restrict__ vt,  // (bh, d, t) bf16
    ushort* __restrict__ ob)        // (b*t, 1024) bf16
{
    __shared__ __align__(16) ushort sK[2][64 * 64];
    __shared__ __align__(16) ushort sV[2][64 * 64];
    __shared__ __align__(16) ushort sP[4][16 * 64];
    const int bh  = blockIdx.x >> 4;
    const int pr  = blockIdx.x & 15;
    const int qtA = pr, qtB = 31 - pr;
    const int lane = threadIdx.x & 63, wv = threadIdx.x >> 6;
    const int lr = lane & 15, lh = lane >> 4;

    const ushort* qrowA = qb + ((size_t)bh * T_ + qtA * 64 + wv * 16 + lr) * D_;
    const ushort* qrowB = qb + ((size_t)bh * T_ + qtB * 64 + wv * 16 + lr) * D_;
    bf16x8 qfA0 = *(const bf16x8*)(qrowA + lh * 8);
    bf16x8 qfA1 = *(const bf16x8*)(qrowA + 32 + lh * 8);
    bf16x8 qfB0 = *(const bf16x8*)(qrowB + lh * 8);
    bf16x8 qfB1 = *(const bf16x8*)(qrowB + 32 + lh * 8);

    const int srow = lane >> 3;
    const int scol = ((lane & 7) ^ srow) * 8;
    const ushort* kbase = kb + (size_t)bh * T_ * D_;
    const ushort* vbase = vt + (size_t)bh * D_ * T_;

    const int sw   = (lr & 7) << 4;
    const int off0 = (16 * lh) ^ sw;
    const int off1 = (64 + 16 * lh) ^ sw;

    f32x4 oA[4] = {}, oB[4] = {};
    float mA = -1e30f, lA = 0.f, mB = -1e30f, lB = 0.f;

    auto redmax = [&](float x) {
        x = fmaxf(x, __int_as_float(__builtin_amdgcn_ds_swizzle(__float_as_int(x), 0x401F)));
        x = fmaxf(x, __shfl_xor(x, 32, 64));
        return x;
    };
    auto redsum = [&](float x) {
        x += __int_as_float(__builtin_amdgcn_ds_swizzle(__float_as_int(x), 0x401F));
        x += __shfl_xor(x, 32, 64);
        return x;
    };

    auto tile = [&](f32x4 (&o)[4], float& mrow, float& lsum,
                    const bf16x8& q0f, const bf16x8& q1f,
                    const char* K0, const char* V0, bool diag) {
        f32x4 s[4];
        __builtin_amdgcn_s_setprio(1);
        #pragma unroll
        for (int nt = 0; nt < 4; ++nt) {
            const char* krow = K0 + (nt * 16 + lr) * 128;
            bf16x8 k0 = *(const bf16x8*)(krow + off0);
            bf16x8 k1 = *(const bf16x8*)(krow + off1);
            f32x4 a = {0.f, 0.f, 0.f, 0.f};
            a = __builtin_amdgcn_mfma_f32_16x16x32_bf16(k0, q0f, a, 0, 0, 0);
            a = __builtin_amdgcn_mfma_f32_16x16x32_bf16(k1, q1f, a, 0, 0, 0);
            s[nt] = a;
        }
        __builtin_amdgcn_s_setprio(0);
        if (diag) {
            #pragma unroll
            for (int nt = 0; nt < 4; ++nt)
                #pragma unroll
                for (int r = 0; r < 4; ++r)
                    if (nt * 16 + lh * 4 + r > wv * 16 + lr) s[nt][r] = -INFINITY;
        }

        float pmax = fmaxf(fmaxf(fmaxf(s[0][0], s[0][1]), fmaxf(s[0][2], s[0][3])),
                           fmaxf(fmaxf(s[1][0], s[1][1]), fmaxf(s[1][2], s[1][3])));
        pmax = fmaxf(pmax, fmaxf(fmaxf(fmaxf(s[2][0], s[2][1]), fmaxf(s[2][2], s[2][3])),
                                 fmaxf(fmaxf(s[3][0], s[3][1]), fmaxf(s[3][2], s[3][3]))));
        pmax = redmax(pmax);

        if (__any(pmax > mrow + 8.f)) {     // defer-max (T13, THR=8, exp2 space)
            float mnew = fmaxf(mrow, pmax);
            float al = __builtin_exp2f(mrow - mnew);
            lsum *= al;
            #pragma unroll
            for (int r = 0; r < 4; ++r) {
                float ar = __shfl(al, lh * 20 + r, 64);
                o[0][r] *= ar; o[1][r] *= ar; o[2][r] *= ar; o[3][r] *= ar;
            }
            mrow = mnew;
        }

        float rsum = 0.f;
        uint pk[8];
        #pragma unroll
        for (int nt = 0; nt < 4; ++nt) {
            float p0 = __builtin_exp2f(s[nt][0] - mrow);
            float p1 = __builtin_exp2f(s[nt][1] - mrow);
            float p2 = __builtin_exp2f(s[nt][2] - mrow);
            float p3 = __builtin_exp2f(s[nt][3] - mrow);
            rsum += (p0 + p1) + (p2 + p3);
            pk[nt * 2]     = packbf(p0, p1);
            pk[nt * 2 + 1] = packbf(p2, p3);
        }
        lsum += redsum(rsum);

        char* P = (char*)sP[wv];
        {
            char* prow = P + lr * 128;
            #pragma unroll
            for (int nt = 0; nt < 4; ++nt) {
                uint2 w; w.x = pk[nt * 2]; w.y = pk[nt * 2 + 1];
                *(uint2*)(prow + ((32 * nt + 8 * lh) ^ sw)) = w;
            }
        }
        asm volatile("" ::: "memory");
        bf16x8 pf0 = *(const bf16x8*)(P + lr * 128 + off0);
        bf16x8 pf1 = *(const bf16x8*)(P + lr * 128 + off1);

        __builtin_amdgcn_s_setprio(1);
        #pragma unroll
        for (int dt = 0; dt < 4; ++dt) {
            const char* vrow = V0 + (dt * 16 + lr) * 128;
            bf16x8 v0 = *(const bf16x8*)(vrow + off0);
            bf16x8 v1 = *(const bf16x8*)(vrow + off1);
            o[dt] = __builtin_amdgcn_mfma_f32_16x16x32_bf16(pf0, v0, o[dt], 0, 0, 0);
            o[dt] = __builtin_amdgcn_mfma_f32_16x16x32_bf16(pf1, v1, o[dt], 0, 0, 0);
        }
        __builtin_amdgcn_s_setprio(0);
    };

    #pragma unroll
    for (int i = 0; i < 2; ++i) {
        int j = i * 4 + wv;
        gload_lds16(kbase + (size_t)(j * 8 + srow) * D_ + scol, &sK[0][j * 512]);
        gload_lds16(vbase + (size_t)(j * 8 + srow) * T_ + scol, &sV[0][j * 512]);
    }
    __syncthreads();

    for (int kt = 0; kt <= qtB; ++kt) {
        const int cur = kt & 1;
        if (kt < qtB) {
            const int nb = cur ^ 1;
            #pragma unroll
            for (int i = 0; i < 2; ++i) {
                int j = i * 4 + wv;
                gload_lds16(kbase + (size_t)((kt + 1) * 64 + j * 8 + srow) * D_ + scol, &sK[nb][j * 512]);
                gload_lds16(vbase + (size_t)(j * 8 + srow) * T_ + (kt + 1) * 64 + scol, &sV[nb][j * 512]);
            }
        }
        const char* K0 = (const char*)sK[cur];
        const char* V0 = (const char*)sV[cur];
        if (kt <= qtA) tile(oA, mA, lA, qfA0, qfA1, K0, V0, kt == qtA);
        tile(oB, mB, lB, qfB0, qfB1, K0, V0, kt == qtB);
        __syncthreads();
    }

    const int b = bh >> 4, h = bh & 15;
    auto writeout = [&](f32x4 (&o)[4], float lsum, int q0) {
        float inv = 1.f / lsum;
        #pragma unroll
        for (int r = 0; r < 4; ++r) {
            float ir = __shfl(inv, lh * 20 + r, 64);
            int q = q0 + lh * 4 + r;
            #pragma unroll
            for (int dt = 0; dt < 4; ++dt)
                ob[((size_t)b * T_ + q) * C_ + h * 64 + dt * 16 + lr] = f2bf(o[dt][r] * ir);
        }
    };
    writeout(oA, lA, qtA * 64 + wv * 16);
    writeout(oB, lB, qtB * 64 + wv * 16);
}

extern "C" void kernel_launch(void* const* d_in, const int* in_sizes, int n_in,
                              void* d_out, int out_size, void* d_ws, size_t ws_size,
                              hipStream_t stream) {
    const float* x     = (const float*)d_in[0];
    const float* w_qkv = (const float*)d_in[1];
    const float* b_qkv = (const float*)d_in[2];
    const float* w_out = (const float*)d_in[3];
    const float* b_out = (const float*)d_in[4];
    float* out = (float*)d_out;

    char* ws = (char*)d_ws;
    ushort* xb     = (ushort*)(ws + 0);           // 16 MB (aliased: attn out reuses after GEMM1)
    ushort* wqkvT  = (ushort*)(ws + 16777216);    // 6 MB
    ushort* woutT  = (ushort*)(ws + 23068672);    // 2 MB
    ushort* qkv    = (ushort*)(ws + 25165824);    // 48 MB
    ushort* vT     = (ushort*)(ws + 75497472);    // 16 MB
    ushort* attn   = xb;
    ushort* qb = qkv;
    ushort* kb = qkv + (size_t)BH_ * T_ * D_;
    ushort* vb = qkv + (size_t)2 * BH_ * T_ * D_;

    const int nx = B_ * T_ * C_;
    cvt_kernel<<<nx / 4 / 256, 256, 0, stream>>>(x, xb, nx);
    transpose_cvt_kernel<<<dim3(3 * C_ / 32, C_ / 32), 256, 0, stream>>>(w_qkv, wqkvT, C_, 3 * C_);
    transpose_cvt_kernel<<<dim3(C_ / 32, C_ / 32), 256, 0, stream>>>(w_out, woutT, C_, C_);
    gemm_hk<4, true><<<dim3(3 * C_ / 256, B_ * T_ / 256), 512, 0, stream>>>(xb, wqkvT, b_qkv, qkv);
    transpose_v_kernel<<<BH_ * (T_ / 64), 256, 0, stream>>>(vb, vT);
    flash_kernel<<<BH_ * 16, 256, 0, stream>>>(qb, kb, vT, attn);
    gemm_hk<2, false><<<dim3(C_ / 128, B_ * T_ / 256), 512, 0, stream>>>(attn, woutT, b_out, out);
}